// Round 2
// baseline (2876.064 us; speedup 1.0000x reference)
//
#include <hip/hip_runtime.h>

#define DEV static __device__ __forceinline__

DEV float sigf(float x) { return 1.0f / (1.0f + __expf(-x)); }
DEV float ftanh(float x) {
  float xc = fminf(fmaxf(x, -9.0f), 9.0f);
  float e = __expf(2.0f * xc);
  return (e - 1.0f) / (e + 1.0f);
}

// ---------------- generic tiled f32 GEMM (NT): out[m][n] = sum_k A[m][k]*B[n][k] + bias[n]
__global__ __launch_bounds__(256) void gemm_nt_bias(
    const float* __restrict__ A, const float* __restrict__ B,
    const float* __restrict__ bias, float* __restrict__ out,
    int M, int N, int K)
{
  __shared__ float As[64][17];
  __shared__ float Bs[64][17];
  const int tid = threadIdx.x;
  const int m0 = blockIdx.y * 64, n0 = blockIdx.x * 64;
  const int lr = tid >> 2;          // 0..63
  const int lk = (tid & 3) << 2;    // 0,4,8,12
  const int ty = tid >> 4, tx = tid & 15;
  float acc[4][4] = {};
  for (int k0 = 0; k0 < K; k0 += 16) {
    float4 a4 = *(const float4*)(A + (size_t)(m0 + lr) * K + k0 + lk);
    float4 b4 = *(const float4*)(B + (size_t)(n0 + lr) * K + k0 + lk);
    As[lr][lk] = a4.x; As[lr][lk + 1] = a4.y; As[lr][lk + 2] = a4.z; As[lr][lk + 3] = a4.w;
    Bs[lr][lk] = b4.x; Bs[lr][lk + 1] = b4.y; Bs[lr][lk + 2] = b4.z; Bs[lr][lk + 3] = b4.w;
    __syncthreads();
#pragma unroll
    for (int kk = 0; kk < 16; ++kk) {
      float av[4], bv[4];
#pragma unroll
      for (int r = 0; r < 4; ++r) av[r] = As[ty * 4 + r][kk];
#pragma unroll
      for (int c = 0; c < 4; ++c) bv[c] = Bs[tx * 4 + c][kk];
#pragma unroll
      for (int r = 0; r < 4; ++r)
#pragma unroll
        for (int c = 0; c < 4; ++c) acc[r][c] = fmaf(av[r], bv[c], acc[r][c]);
    }
    __syncthreads();
  }
#pragma unroll
  for (int r = 0; r < 4; ++r) {
    int m = m0 + ty * 4 + r;
#pragma unroll
    for (int c = 0; c < 4; ++c) {
      int n = n0 + tx * 4 + c;
      out[(size_t)m * N + n] = acc[r][c] + bias[n];
    }
  }
}

// ---------------- build float4-transposed h: dstT[k4][b] = h[b][4k4..4k4+3]
__global__ void transpose_h(const float* __restrict__ src /*[32][512]*/,
                            float* __restrict__ dstT /*[128][32] float4*/)
{
  int idx = blockIdx.x * 256 + threadIdx.x;   // 4096 float4s
  if (idx < 4096) {
    int k4 = idx >> 5, b = idx & 31;
    ((float4*)dstT)[idx] = ((const float4*)src)[b * 128 + k4];
  }
}

// ---------------- LSTM1: pre1 = x_t + h_prev @ U^T ; cell -> h1, c1
__global__ __launch_bounds__(256) void lstm1_kernel(
    const float* __restrict__ xt,       // [32][2048]
    const float* __restrict__ hprevT,   // [128][32] float4 (as floats)
    const float* __restrict__ c_prev,   // [32][512]
    const float* __restrict__ U,        // [2048][512]
    const float* __restrict__ ymask_t,  // [32]
    float* __restrict__ h1, float* __restrict__ h1T, float* __restrict__ c1)
{
  const int tid = threadIdx.x;
  const int b = tid & 31;
  const int slot = tid >> 5;
  const int jl = slot & 3;
  const int pair = slot >> 2;           // 0:(i,f) 1:(o,g)
  const int j = blockIdx.x * 4 + jl;
  const int g0 = pair ? 1024 : 0;
  const float* u0 = U + (size_t)(g0 + j) * 512;
  const float* u1 = U + (size_t)(g0 + 512 + j) * 512;
  const float4* hT4 = (const float4*)hprevT;
  float a0 = xt[b * 2048 + g0 + j];
  float a1 = xt[b * 2048 + g0 + 512 + j];
#pragma unroll 4
  for (int k4 = 0; k4 < 128; ++k4) {
    float4 h4 = hT4[k4 * 32 + b];
    float4 u04 = *(const float4*)(u0 + k4 * 4);
    float4 u14 = *(const float4*)(u1 + k4 * 4);
    a0 = fmaf(h4.x, u04.x, fmaf(h4.y, u04.y, fmaf(h4.z, u04.z, fmaf(h4.w, u04.w, a0))));
    a1 = fmaf(h4.x, u14.x, fmaf(h4.y, u14.y, fmaf(h4.z, u14.z, fmaf(h4.w, u14.w, a1))));
  }
  __shared__ float sIF[4][32][2];
  __shared__ float sOG[4][32][2];
  if (pair == 0) { sIF[jl][b][0] = a0; sIF[jl][b][1] = a1; }
  else           { sOG[jl][b][0] = a0; sOG[jl][b][1] = a1; }
  __syncthreads();
  if (pair == 0) {
    float iv = sIF[jl][b][0], fv = sIF[jl][b][1];
    float ov = sOG[jl][b][0], gv = sOG[jl][b][1];
    float cold = c_prev[b * 512 + j];
    float cn = sigf(fv) * cold + sigf(iv) * tanhf(gv);
    float hn = sigf(ov) * tanhf(cn);
    float ym = ymask_t[b];
    float hfall = hprevT[(j >> 2) * 128 + b * 4 + (j & 3)];
    float hm = ym * hn + (1.0f - ym) * hfall;
    h1[b * 512 + j] = hm;
    h1T[(j >> 2) * 128 + b * 4 + (j & 3)] = hm;
    c1[b * 512 + j] = cn;     // c1 is NOT masked (matches reference)
  }
}

// ---------------- hproj = h1 @ W_comb_att^T  [32][1024]
__global__ __launch_bounds__(256) void hproj_kernel(
    const float* __restrict__ h1T, const float* __restrict__ Wcomb /*[1024][512]*/,
    float* __restrict__ hproj /*[32][1024]*/)
{
  const int tid = threadIdx.x;
  const int b = tid & 31;
  const int d = blockIdx.x * 8 + (tid >> 5);
  const float* wr = Wcomb + (size_t)d * 512;
  const float4* hT4 = (const float4*)h1T;
  float acc = 0.f;
#pragma unroll 4
  for (int k4 = 0; k4 < 128; ++k4) {
    float4 h4 = hT4[k4 * 32 + b];
    float4 w4 = *(const float4*)(wr + k4 * 4);
    acc = fmaf(h4.x, w4.x, fmaf(h4.y, w4.y, fmaf(h4.z, w4.z, fmaf(h4.w, w4.w, acc))));
  }
  hproj[b * 1024 + d] = acc;
}

// ---------------- score[t][b] = xm[t,b] * sum_c tanh(pctx[t,b,c] + hproj[b,c]) * U_att[c]
__global__ __launch_bounds__(256) void score_kernel(
    const float* __restrict__ pctx, const float* __restrict__ hproj,
    const float* __restrict__ U_att, const float* __restrict__ x_mask,
    float* __restrict__ score /*[128][32]*/)
{
  const int t = blockIdx.x;
  const int b = blockIdx.y * 4 + (threadIdx.x >> 6);
  const int lane = threadIdx.x & 63;
  const float4* pr = (const float4*)(pctx + ((size_t)t * 32 + b) * 1024);
  const float4* hp = (const float4*)(hproj + (size_t)b * 1024);
  const float4* ua = (const float4*)U_att;
  float acc = 0.f;
#pragma unroll
  for (int i = 0; i < 4; ++i) {
    int c4 = i * 64 + lane;
    float4 p = pr[c4], h = hp[c4], u = ua[c4];
    acc += ftanh(p.x + h.x) * u.x + ftanh(p.y + h.y) * u.y
         + ftanh(p.z + h.z) * u.z + ftanh(p.w + h.w) * u.w;
  }
#pragma unroll
  for (int off = 32; off > 0; off >>= 1) acc += __shfl_down(acc, off);
  if (lane == 0) score[t * 32 + b] = acc * x_mask[t * 32 + b];
}

// ---------------- softmax over t + atted[b][c] ; writes atts output slice + transposed copy
__global__ __launch_bounds__(256) void atted_kernel(
    const float* __restrict__ score, const float* __restrict__ x_mask,
    const float* __restrict__ context, float* __restrict__ atts_t /*[32][1024]*/,
    float* __restrict__ attedT /*[256][32] float4*/)
{
  const int b = blockIdx.x, cc = blockIdx.y;
  const int tid = threadIdx.x;
  __shared__ float sc[128];
  __shared__ float red[2];
  if (tid < 128) sc[tid] = score[tid * 32 + b];
  __syncthreads();
  if (tid < 64) {
    float m = fmaxf(sc[tid], sc[tid + 64]);
#pragma unroll
    for (int off = 32; off > 0; off >>= 1) m = fmaxf(m, __shfl_down(m, off));
    if (tid == 0) red[0] = m;
  }
  __syncthreads();
  float mx = red[0];
  if (tid < 128) sc[tid] = __expf(sc[tid] - mx) * x_mask[tid * 32 + b];
  __syncthreads();
  if (tid < 64) {
    float s = sc[tid] + sc[tid + 64];
#pragma unroll
    for (int off = 32; off > 0; off >>= 1) s += __shfl_down(s, off);
    if (tid == 0) red[1] = s;
  }
  __syncthreads();
  const float inv = 1.0f / red[1];
  const int c4 = tid & 31, tg = tid >> 5;
  const float4* ctx4 = (const float4*)context;
  float4 acc = make_float4(0.f, 0.f, 0.f, 0.f);
  for (int t = tg; t < 128; t += 8) {
    float a = sc[t] * inv;
    float4 v = ctx4[((size_t)t * 32 + b) * 256 + cc * 32 + c4];
    acc.x = fmaf(a, v.x, acc.x); acc.y = fmaf(a, v.y, acc.y);
    acc.z = fmaf(a, v.z, acc.z); acc.w = fmaf(a, v.w, acc.w);
  }
  __shared__ float4 part[8][32];
  part[tg][c4] = acc;
  __syncthreads();
  if (tid < 32) {
    float4 tot = part[0][tid];
#pragma unroll
    for (int g = 1; g < 8; ++g) {
      float4 p = part[g][tid];
      tot.x += p.x; tot.y += p.y; tot.z += p.z; tot.w += p.w;
    }
    ((float4*)(atts_t + (size_t)b * 1024 + cc * 128))[tid] = tot;
    ((float4*)attedT)[(size_t)(cc * 32 + tid) * 32 + b] = tot;
  }
}

// ---------------- LSTM2: pre2 = h1 @ Ux^T + atted @ Wx^T + bx ; cell -> h2, c2 (outputs)
__global__ __launch_bounds__(256) void lstm2_kernel(
    const float* __restrict__ h1, const float* __restrict__ h1T,
    const float* __restrict__ c1, const float* __restrict__ attedT,
    const float* __restrict__ Ux, const float* __restrict__ Wx,
    const float* __restrict__ bx, const float* __restrict__ ymask_t,
    float* __restrict__ hs_t, float* __restrict__ cs_t,
    float* __restrict__ hprevT_next)
{
  const int tid = threadIdx.x;
  const int b = tid & 31;
  const int slot = tid >> 5;
  const int jl = slot & 3;
  const int pair = slot >> 2;
  const int j = blockIdx.x * 4 + jl;
  const int g0 = pair ? 1024 : 0;
  const float* ux0 = Ux + (size_t)(g0 + j) * 512;
  const float* ux1 = Ux + (size_t)(g0 + 512 + j) * 512;
  const float* wx0 = Wx + (size_t)(g0 + j) * 1024;
  const float* wx1 = Wx + (size_t)(g0 + 512 + j) * 1024;
  float a0 = bx[g0 + j], a1 = bx[g0 + 512 + j];
  const float4* hT4 = (const float4*)h1T;
#pragma unroll 4
  for (int k4 = 0; k4 < 128; ++k4) {
    float4 h4 = hT4[k4 * 32 + b];
    float4 u04 = *(const float4*)(ux0 + k4 * 4);
    float4 u14 = *(const float4*)(ux1 + k4 * 4);
    a0 = fmaf(h4.x, u04.x, fmaf(h4.y, u04.y, fmaf(h4.z, u04.z, fmaf(h4.w, u04.w, a0))));
    a1 = fmaf(h4.x, u14.x, fmaf(h4.y, u14.y, fmaf(h4.z, u14.z, fmaf(h4.w, u14.w, a1))));
  }
  const float4* aT4 = (const float4*)attedT;
#pragma unroll 4
  for (int c4 = 0; c4 < 256; ++c4) {
    float4 v4 = aT4[c4 * 32 + b];
    float4 w04 = *(const float4*)(wx0 + c4 * 4);
    float4 w14 = *(const float4*)(wx1 + c4 * 4);
    a0 = fmaf(v4.x, w04.x, fmaf(v4.y, w04.y, fmaf(v4.z, w04.z, fmaf(v4.w, w04.w, a0))));
    a1 = fmaf(v4.x, w14.x, fmaf(v4.y, w14.y, fmaf(v4.z, w14.z, fmaf(v4.w, w14.w, a1))));
  }
  __shared__ float sIF[4][32][2];
  __shared__ float sOG[4][32][2];
  if (pair == 0) { sIF[jl][b][0] = a0; sIF[jl][b][1] = a1; }
  else           { sOG[jl][b][0] = a0; sOG[jl][b][1] = a1; }
  __syncthreads();
  if (pair == 0) {
    float iv = sIF[jl][b][0], fv = sIF[jl][b][1];
    float ov = sOG[jl][b][0], gv = sOG[jl][b][1];
    float cold = c1[b * 512 + j];
    float cn = sigf(fv) * cold + sigf(iv) * tanhf(gv);
    float hn = sigf(ov) * tanhf(cn);
    float ym = ymask_t[b];
    float hf = h1[b * 512 + j];
    float hm = ym * hn + (1.0f - ym) * hf;
    hs_t[b * 512 + j] = hm;
    cs_t[b * 512 + j] = cn;
    hprevT_next[(j >> 2) * 128 + b * 4 + (j & 3)] = hm;
  }
}

extern "C" void kernel_launch(void* const* d_in, const int* in_sizes, int n_in,
                              void* d_out, int out_size, void* d_ws, size_t ws_size,
                              hipStream_t stream)
{
  const float* y_emb   = (const float*)d_in[0];
  const float* context = (const float*)d_in[1];
  const float* init_h  = (const float*)d_in[2];
  const float* init_c  = (const float*)d_in[3];
  const float* x_mask  = (const float*)d_in[4];
  const float* y_mask  = (const float*)d_in[5];
  const float* W       = (const float*)d_in[6];
  const float* U       = (const float*)d_in[7];
  const float* bvec    = (const float*)d_in[8];
  const float* Wx      = (const float*)d_in[9];
  const float* Ux      = (const float*)d_in[10];
  const float* bx      = (const float*)d_in[11];
  const float* Wc      = (const float*)d_in[12];
  const float* b_att   = (const float*)d_in[13];
  const float* Wcomb   = (const float*)d_in[14];
  const float* U_att   = (const float*)d_in[15];

  float* out  = (float*)d_out;
  float* hs   = out;                          // [32][32][512]
  float* cs   = out + (size_t)32 * 32 * 512;  // [32][32][512]
  float* atts = out + (size_t)2 * 32 * 32 * 512; // [32][32][1024]

  float* ws    = (float*)d_ws;
  float* pctx  = ws;                 // 4194304 floats [128][32][1024]
  float* x     = pctx + 4194304;     // 2097152 floats [32][32][2048]
  float* h1    = x + 2097152;        // 16384
  float* c1    = h1 + 16384;         // 16384
  float* hproj = c1 + 16384;         // 32768
  float* score = hproj + 32768;      // 4096
  float* hT    = score + 4096;       // 16384 (h_prev transposed, float4 [128][32])
  float* h1T   = hT + 16384;         // 16384
  float* attT  = h1T + 16384;        // 32768 (atted transposed, float4 [256][32])

  gemm_nt_bias<<<dim3(1024 / 64, 4096 / 64), 256, 0, stream>>>(context, Wc, b_att, pctx, 4096, 1024, 1024);
  gemm_nt_bias<<<dim3(2048 / 64, 1024 / 64), 256, 0, stream>>>(y_emb, W, bvec, x, 1024, 2048, 256);
  transpose_h<<<16, 256, 0, stream>>>(init_h, hT);

  for (int t = 0; t < 32; ++t) {
    const float* cp = t ? cs + (size_t)(t - 1) * 16384 : init_c;
    lstm1_kernel<<<128, 256, 0, stream>>>(x + (size_t)t * 65536, hT, cp, U, y_mask + t * 32, h1, h1T, c1);
    hproj_kernel<<<128, 256, 0, stream>>>(h1T, Wcomb, hproj);
    score_kernel<<<dim3(128, 8), 256, 0, stream>>>(pctx, hproj, U_att, x_mask, score);
    atted_kernel<<<dim3(32, 8), 256, 0, stream>>>(score, x_mask, context, atts + (size_t)t * 32768, attT);
    lstm2_kernel<<<128, 256, 0, stream>>>(h1, h1T, c1, attT, Ux, Wx, bx, y_mask + t * 32,
                                          hs + (size_t)t * 16384, cs + (size_t)t * 16384, hT);
  }
}